// Round 7
// baseline (2627.172 us; speedup 1.0000x reference)
//
#include <hip/hip_runtime.h>
#include <stdint.h>
#include <stddef.h>

#define S_LEN 2048
#define BATCH 32
#define NIN   256
#define NH    256
#define NG    768   // 3*NH

typedef _Float16 half2_t __attribute__((ext_vector_type(2)));
typedef _Float16 half8_t __attribute__((ext_vector_type(8)));
typedef int      int16v  __attribute__((ext_vector_type(16)));

#if __has_builtin(__builtin_amdgcn_exp2f)
#define EXP2F(x) __builtin_amdgcn_exp2f(x)
#else
#define EXP2F(x) exp2f(x)
#endif

static __device__ __forceinline__ float fdot2(half2_t a, half2_t b, float c) {
  return __builtin_amdgcn_fdot2(a, b, c, false);
}
static __device__ __forceinline__ half2_t pack2(float lo, float hi) {
  half2_t r; r[0] = (_Float16)lo; r[1] = (_Float16)hi; return r;
}
static __device__ __forceinline__ float sigmoid_fast(float x) {
  float e = EXP2F(-1.44269504088896340736f * x);
  return 1.0f / (1.0f + e);
}
static __device__ __forceinline__ float tanh_fast(float x) {
  float e = EXP2F(2.88539008177792681472f * x);
  return 1.0f - 2.0f / (1.0f + e);
}

// quad reduction via DPP quad_perm (register-file exchange, no LDS, no
// barrier): xor1 then xor2 -> all 4 lanes hold the full 4-way sum,
// bit-identical.
static __device__ __forceinline__ float quad_sum(float v) {
  int y1 = __builtin_amdgcn_mov_dpp(__builtin_bit_cast(int, v), 0xB1, 0xF, 0xF, true);
  float s = v + __builtin_bit_cast(float, y1);
  int y2 = __builtin_amdgcn_mov_dpp(__builtin_bit_cast(int, s), 0x4E, 0xF, 0xF, true);
  return s + __builtin_bit_cast(float, y2);
}

// bit-cast helpers: element extracts use LITERAL indices / fields -> pure SSA
#define BH(x)    __builtin_bit_cast(half2_t, (x))
#define BW(W, e) __builtin_bit_cast(half2_t, (int)((W)[e]))

// ---- xproj path ----
// R7: WEIGHT AS SRC0 (fdot2 commutative -> bit-identical). On CDNA, AGPR
// sources are legal in src0 but not vsrc1; if the allocator demoted the
// pinned weights to AGPRs (R4: VGPR_Count=124 < 192-dword demand), src0
// placement lets the HW read them directly instead of paying one
// v_accvgpr_read shuttle per use per step.
#define DOT16(W, i0) do {                                                     \
    int4 q0 = hls[(i0) + 0], q1 = hls[(i0) + 1];                              \
    int4 q2 = hls[(i0) + 2], q3 = hls[(i0) + 3];                              \
    a0 = fdot2(BW(W, 0),  BH(q0.x), a0); a1 = fdot2(BW(W, 1),  BH(q0.y), a1);\
    a2 = fdot2(BW(W, 2),  BH(q0.z), a2); a3 = fdot2(BW(W, 3),  BH(q0.w), a3);\
    a0 = fdot2(BW(W, 4),  BH(q1.x), a0); a1 = fdot2(BW(W, 5),  BH(q1.y), a1);\
    a2 = fdot2(BW(W, 6),  BH(q1.z), a2); a3 = fdot2(BW(W, 7),  BH(q1.w), a3);\
    a0 = fdot2(BW(W, 8),  BH(q2.x), a0); a1 = fdot2(BW(W, 9),  BH(q2.y), a1);\
    a2 = fdot2(BW(W, 10), BH(q2.z), a2); a3 = fdot2(BW(W, 11), BH(q2.w), a3);\
    a0 = fdot2(BW(W, 12), BH(q3.x), a0); a1 = fdot2(BW(W, 13), BH(q3.y), a1);\
    a2 = fdot2(BW(W, 14), BH(q3.z), a2); a3 = fdot2(BW(W, 15), BH(q3.w), a3);\
  } while (0)

// ---- gru path: one 16B h chunk (4 half2) against 6 row-slices (2j x 3 gates).
// Weight as src0 (see above). Same accumulation order as R4 -> bit-identical.
#define DOT6(q, U0, U1, U2, U3, U4, U5, o) do {                               \
    a0 = fdot2(BW(U0,(o)+0), BH(q.x), a0); a1 = fdot2(BW(U1,(o)+0), BH(q.x), a1);\
    a2 = fdot2(BW(U2,(o)+0), BH(q.x), a2); a3 = fdot2(BW(U3,(o)+0), BH(q.x), a3);\
    a4 = fdot2(BW(U4,(o)+0), BH(q.x), a4); a5 = fdot2(BW(U5,(o)+0), BH(q.x), a5);\
    a0 = fdot2(BW(U0,(o)+1), BH(q.y), a0); a1 = fdot2(BW(U1,(o)+1), BH(q.y), a1);\
    a2 = fdot2(BW(U2,(o)+1), BH(q.y), a2); a3 = fdot2(BW(U3,(o)+1), BH(q.y), a3);\
    a4 = fdot2(BW(U4,(o)+1), BH(q.y), a4); a5 = fdot2(BW(U5,(o)+1), BH(q.y), a5);\
    a0 = fdot2(BW(U0,(o)+2), BH(q.z), a0); a1 = fdot2(BW(U1,(o)+2), BH(q.z), a1);\
    a2 = fdot2(BW(U2,(o)+2), BH(q.z), a2); a3 = fdot2(BW(U3,(o)+2), BH(q.z), a3);\
    a4 = fdot2(BW(U4,(o)+2), BH(q.z), a4); a5 = fdot2(BW(U5,(o)+2), BH(q.z), a5);\
    a0 = fdot2(BW(U0,(o)+3), BH(q.w), a0); a1 = fdot2(BW(U1,(o)+3), BH(q.w), a1);\
    a2 = fdot2(BW(U2,(o)+3), BH(q.w), a2); a3 = fdot2(BW(U3,(o)+3), BH(q.w), a3);\
    a4 = fdot2(BW(U4,(o)+3), BH(q.w), a4); a5 = fdot2(BW(U5,(o)+3), BH(q.w), a5);\
  } while (0)

#define LDW(W, o) do {                                                        \
    int4 q0 = wsrc[(o) + 0], q1 = wsrc[(o) + 1];                              \
    int4 q2 = wsrc[(o) + 2], q3 = wsrc[(o) + 3];                              \
    W = (int16v){q0.x, q0.y, q0.z, q0.w, q1.x, q1.y, q1.z, q1.w,              \
                 q2.x, q2.y, q2.z, q2.w, q3.x, q3.y, q3.z, q3.w};             \
  } while (0)

// ---------------- prep: input f32 -> f16 ----------------
__global__ __launch_bounds__(256) void prep_in_kernel(const float* __restrict__ in,
                                                      _Float16* __restrict__ in16) {
  size_t v = (size_t)blockIdx.x * 256 + threadIdx.x;
  const float4* p4 = (const float4*)in;
  float4 a = p4[v * 2 + 0];
  float4 b = p4[v * 2 + 1];
  half8_t o;
  o[0] = (_Float16)a.x; o[1] = (_Float16)a.y; o[2] = (_Float16)a.z; o[3] = (_Float16)a.w;
  o[4] = (_Float16)b.x; o[5] = (_Float16)b.y; o[6] = (_Float16)b.z; o[7] = (_Float16)b.w;
  ((half8_t*)in16)[v] = o;
}

// ---------------- prep: weights ----------------
// whh3 layout (G=6/S=4): thread tid = j1*4+c owns 192 contiguous dwords
// [d][kk], d = gate*2+jj in 0..5, kk in 0..31: half2 of
// W_hh[row = gate*256 + 2*j1 + jj][col = 64*c + 2*kk .. +1].
__global__ __launch_bounds__(256) void prep_w_kernel(const float* __restrict__ W_ih,
                                                     const float* __restrict__ W_hh,
                                                     const float* __restrict__ b_ih,
                                                     const float* __restrict__ b_hh,
                                                     half2_t* __restrict__ whh3,
                                                     half2_t* __restrict__ wih2,
                                                     float* __restrict__ bias) {
  int idx = blockIdx.x * 256 + threadIdx.x;
  if (idx < 128 * NG) {                      // 98304 dwords = 384 KiB
    int tid = idx / 192;
    int r   = idx - tid * 192;
    int d   = r >> 5, kk = r & 31;
    int gate = d >> 1, jj = d & 1;
    int c  = tid & 3, j1 = tid >> 2;
    int row = gate * NH + 2 * j1 + jj;
    int col = 64 * c + 2 * kk;
    whh3[idx] = pack2(W_hh[(size_t)row * NH + col], W_hh[(size_t)row * NH + col + 1]);
  } else if (idx < 2 * 128 * NG) {
    int i2 = idx - 128 * NG;
    int g = i2 >> 7, kk = i2 & 127;
    wih2[(size_t)g * 128 + kk] = pack2(W_ih[(size_t)g * NIN + 2 * kk], W_ih[(size_t)g * NIN + 2 * kk + 1]);
  } else if (idx < 2 * 128 * NG + NG) {
    int g = idx - 2 * 128 * NG;
    bias[g] = b_ih[g] + b_hh[g];
  }
}

// ---------------- x_proj GEMM (weight-as-src0) ----------------
__global__
__attribute__((amdgpu_flat_work_group_size(768, 768), amdgpu_waves_per_eu(3, 3)))
void xproj_kernel(const _Float16* __restrict__ in16,
                  const half2_t* __restrict__ wih2,
                  const float* __restrict__ bias,
                  float* __restrict__ xp_out) {
  __shared__ char occ_pad[86016];
  {
    unsigned lp = (unsigned)(uintptr_t)&occ_pad[0];
    asm volatile("" :: "v"(lp));
  }
  const int g = threadIdx.x;
  const int row0 = blockIdx.x * 64;
  const float bg = bias[g];

  int16v w0, w1, w2, w3, w4, w5, w6, w7;
  {
    const int4* wsrc = (const int4*)(wih2 + (size_t)g * 128);
    LDW(w0, 0);  LDW(w1, 4);  LDW(w2, 8);  LDW(w3, 12);
    LDW(w4, 16); LDW(w5, 20); LDW(w6, 24); LDW(w7, 28);
  }
  asm volatile("" : "+v"(w0), "+v"(w1), "+v"(w2), "+v"(w3),
                    "+v"(w4), "+v"(w5), "+v"(w6), "+v"(w7));

  for (int r = 0; r < 64; ++r) {
    const int row = row0 + r;
    const int4* hls = (const int4*)(in16 + (size_t)row * NIN);
    float a0 = 0.f, a1 = 0.f, a2 = 0.f, a3 = 0.f;
    DOT16(w0, 0);  DOT16(w1, 4);  DOT16(w2, 8);  DOT16(w3, 12);
    DOT16(w4, 16); DOT16(w5, 20); DOT16(w6, 24); DOT16(w7, 28);
    xp_out[(size_t)row * NG + g] = (a0 + a1) + (a2 + a3) + bg;
  }
}

// ---------------- recurrence: G=6/S=4, weight-as-src0 ----------------
// R7 (session R15): base = R4 (passing, 2272us). R6's granular tied-asm pin
// corrupted data (compiler bug with many tied ext-vector operands) -> revert.
// Single change vs R4: fdot2 operand order swapped so the WEIGHT is src0.
// Rationale: R4's VGPR_Count=124 proves the 192 weight dwords live in AGPRs.
// Two degenerate explanations for the ~2x VALU issue vs model: (a) one
// v_accvgpr_read shuttle per weight use (AGPR illegal in vsrc1), (b) 4-cyc
// dot issue. fdot2 is commutative; with weights in src0, (a) vanishes at
// zero cost, (b) predicts no change. This round distinguishes them.
__global__
__attribute__((amdgpu_flat_work_group_size(512, 512), amdgpu_waves_per_eu(2, 2)))
void gru_kernel(const float* __restrict__ xp,
                const half2_t* __restrict__ whh3,
                float* __restrict__ out) {
  const int b   = blockIdx.x;
  const int tid = threadIdx.x;
  const int c   = tid & 3;        // K-quarter
  const int j1  = tid >> 2;       // j-pair index 0..127
  const int jj  = c & 1;          // owned j parity
  const int jmine = 2 * j1 + jj;  // this lane's h row (lanes c, c+2 redundant)

  int16v W0a, W0b, W1a, W1b, W2a, W2b, W3a, W3b, W4a, W4b, W5a, W5b;
  {
    const int4* wsrc = (const int4*)(whh3 + (size_t)tid * 192);
    LDW(W0a, 0);  LDW(W0b, 4);  LDW(W1a, 8);  LDW(W1b, 12);
    LDW(W2a, 16); LDW(W2b, 20); LDW(W3a, 24); LDW(W3b, 28);
    LDW(W4a, 32); LDW(W4b, 36); LDW(W5a, 40); LDW(W5b, 44);
  }
  asm volatile("" : "+v"(W0a), "+v"(W0b), "+v"(W1a), "+v"(W1b),
                    "+v"(W2a), "+v"(W2b), "+v"(W3a), "+v"(W3b),
                    "+v"(W4a), "+v"(W4b), "+v"(W5a), "+v"(W5b));

  // 2 buffers x 4 chunks x 144 B (chunk = 64 f16 + 16 B pad) = 1152 B
  __shared__ __attribute__((aligned(16))) char smh[1152];
  if (tid < 288) ((int*)smh)[tid] = 0;

  const float* xq = xp + (size_t)b * NG + jmine;
  float xr_c = xq[0], xz_c = xq[NH], xn_c = xq[2 * NH];
  xq += (size_t)BATCH * NG;
  float* op = out + (size_t)b * NH + jmine;

  const int wofs = 144 * (jmine >> 6) + 2 * (jmine & 63);  // h write offset

  float h = 0.f;
  __syncthreads();

  for (int t = 0; t < S_LEN; ++t) {
    // prefetch xp row t+1 (t=2047 overruns into in16 region: valid, unused)
    float xr_n = xq[0], xz_n = xq[NH], xn_n = xq[2 * NH];

    const char* hb = smh + (t & 1) * 576 + c * 144;
    float a0 = 0.f, a1 = 0.f, a2 = 0.f, a3 = 0.f, a4 = 0.f, a5 = 0.f;
    int4 q0 = *(const int4*)(hb +   0), q1 = *(const int4*)(hb +  16);
    int4 q2 = *(const int4*)(hb +  32), q3 = *(const int4*)(hb +  48);
    int4 q4 = *(const int4*)(hb +  64), q5 = *(const int4*)(hb +  80);
    int4 q6 = *(const int4*)(hb +  96), q7 = *(const int4*)(hb + 112);
    DOT6(q0, W0a, W1a, W2a, W3a, W4a, W5a, 0);
    DOT6(q1, W0a, W1a, W2a, W3a, W4a, W5a, 4);
    DOT6(q2, W0a, W1a, W2a, W3a, W4a, W5a, 8);
    DOT6(q3, W0a, W1a, W2a, W3a, W4a, W5a, 12);
    DOT6(q4, W0b, W1b, W2b, W3b, W4b, W5b, 0);
    DOT6(q5, W0b, W1b, W2b, W3b, W4b, W5b, 4);
    DOT6(q6, W0b, W1b, W2b, W3b, W4b, W5b, 8);
    DOT6(q7, W0b, W1b, W2b, W3b, W4b, W5b, 12);

    // 4-way K reduction in-register; every lane gets full sums
    float s0 = quad_sum(a0), s1 = quad_sum(a1);
    float s2 = quad_sum(a2), s3 = quad_sum(a3);
    float s4 = quad_sum(a4), s5 = quad_sum(a5);
    float mvr = jj ? s1 : s0;
    float mvz = jj ? s3 : s2;
    float mvn = jj ? s5 : s4;

    float r = sigmoid_fast(xr_c + mvr);
    float z = sigmoid_fast(xz_c + mvz);
    float n = tanh_fast(xn_c + mvn + r * mvn);  // torch quirk: mv_n enters twice
    h = z * (h - n) + n;

    if (c < 2) {
      op[0] = h;
      *(_Float16*)(smh + (((t + 1) & 1) * 576) + wofs) = (_Float16)h;
    }
    // h ds_write visible to all waves; no vmcnt drain (stores stay in flight)
    asm volatile("s_waitcnt lgkmcnt(0)\n\ts_barrier" ::: "memory");

    xr_c = xr_n; xz_c = xz_n; xn_c = xn_n;
    xq += (size_t)BATCH * NG;
    op += (size_t)BATCH * NH;
  }

  if (c < 2) out[(size_t)S_LEN * BATCH * NH + (size_t)b * NH + jmine] = h;
}

extern "C" void kernel_launch(void* const* d_in, const int* in_sizes, int n_in,
                              void* d_out, int out_size, void* d_ws, size_t ws_size,
                              hipStream_t stream) {
  const float* input = (const float*)d_in[0];
  const float* W_ih  = (const float*)d_in[1];
  const float* W_hh  = (const float*)d_in[2];
  const float* b_ih  = (const float*)d_in[3];
  const float* b_hh  = (const float*)d_in[4];
  float* out = (float*)d_out;

  const size_t SB = (size_t)S_LEN * BATCH;           // 65536
  const size_t xp_b   = SB * NG * 4;                 // 192 MiB
  const size_t in16_b = SB * NIN * 2;                // 32 MiB
  const size_t w_b    = (size_t)128 * NG * 4;        // 384 KiB each

  char* p = (char*)d_ws;
  float*    xp    = (float*)p;                p += xp_b;
  _Float16* in16  = (_Float16*)p;             p += in16_b;
  half2_t*  whh3  = (half2_t*)p;              p += w_b;
  half2_t*  wih2  = (half2_t*)p;              p += w_b;
  float*    bias  = (float*)p;

  prep_in_kernel<<<8192, 256, 0, stream>>>(input, in16);
  prep_w_kernel<<<(2 * 128 * NG + NG + 255) / 256, 256, 0, stream>>>(W_ih, W_hh, b_ih, b_hh,
                                                                     whh3, wih2, bias);
  xproj_kernel<<<1024, 768, 0, stream>>>(in16, wih2, bias, xp);
  gru_kernel<<<BATCH, 512, 0, stream>>>(xp, whh3, out);
  (void)out_size; (void)n_in; (void)in_sizes; (void)ws_size;
}

// Round 8
// 2362.053 us; speedup vs baseline: 1.1122x; 1.1122x over previous
//
#include <hip/hip_runtime.h>
#include <stdint.h>
#include <stddef.h>

#define S_LEN 2048
#define BATCH 32
#define NIN   256
#define NH    256
#define NG    768   // 3*NH
#define GRUB  32    // gru role blocks
#define XPB   2048  // xproj role blocks (32 rows = 1 step each)

typedef _Float16 half2_t __attribute__((ext_vector_type(2)));
typedef _Float16 half8_t __attribute__((ext_vector_type(8)));
typedef int      int16v  __attribute__((ext_vector_type(16)));
typedef int      int4v   __attribute__((ext_vector_type(4)));

#if __has_builtin(__builtin_amdgcn_exp2f)
#define EXP2F(x) __builtin_amdgcn_exp2f(x)
#else
#define EXP2F(x) exp2f(x)
#endif

static __device__ __forceinline__ float fdot2(half2_t a, half2_t b, float c) {
  return __builtin_amdgcn_fdot2(a, b, c, false);
}
static __device__ __forceinline__ half2_t pack2(float lo, float hi) {
  half2_t r; r[0] = (_Float16)lo; r[1] = (_Float16)hi; return r;
}
static __device__ __forceinline__ float sigmoid_fast(float x) {
  float e = EXP2F(-1.44269504088896340736f * x);
  return 1.0f / (1.0f + e);
}
static __device__ __forceinline__ float tanh_fast(float x) {
  float e = EXP2F(2.88539008177792681472f * x);
  return 1.0f - 2.0f / (1.0f + e);
}
static __device__ __forceinline__ float dpp_xor1(float v) {
  return __builtin_bit_cast(float,
    __builtin_amdgcn_mov_dpp(__builtin_bit_cast(int, v), 0xB1, 0xF, 0xF, true));
}
static __device__ __forceinline__ float dpp_xor2(float v) {
  return __builtin_bit_cast(float,
    __builtin_amdgcn_mov_dpp(__builtin_bit_cast(int, v), 0x4E, 0xF, 0xF, true));
}

// 12 ready-flags in one shot, device-coherent (sc0 sc1 bypasses L1+XCD-L2 so
// cross-XCD producer flags are never stale-cached). One vmcnt(0) total.
static __device__ __forceinline__ int flags_all12(const int* p) {
  int4v a, b, c;
  asm volatile("global_load_dwordx4 %0, %3, off sc0 sc1\n"
               "global_load_dwordx4 %1, %4, off sc0 sc1\n"
               "global_load_dwordx4 %2, %5, off sc0 sc1\n"
               "s_waitcnt vmcnt(0)"
               : "=v"(a), "=v"(b), "=v"(c)
               : "v"(p), "v"(p + 4), "v"(p + 8)
               : "memory");
  int all = a.x & a.y & a.z & a.w;
  all &= b.x & b.y & b.z & b.w;
  all &= c.x & c.y & c.z & c.w;
  return all;
}
// spin until flags[base .. base+11] all set (sentinels >2047 are pre-set to 1)
#define FLAGWAIT(BASEP) do {                                                  \
    while (!flags_all12(BASEP)) __builtin_amdgcn_s_sleep(16);                 \
  } while (0)

// bit-cast helpers: element extracts use LITERAL indices -> pure SSA
#define BH(x)    __builtin_bit_cast(half2_t, (x))
#define BW(W, e) __builtin_bit_cast(half2_t, (int)((W)[e]))

// one 16B operand chunk (4 half2) against 6 row-slices (2j x 3 gates).
// Weight as src0. Accumulator reuse distance 6 -> no VALU dep stalls.
#define DOT6(q, U0, U1, U2, U3, U4, U5, o) do {                               \
    a0 = fdot2(BW(U0,(o)+0), BH(q.x), a0); a1 = fdot2(BW(U1,(o)+0), BH(q.x), a1);\
    a2 = fdot2(BW(U2,(o)+0), BH(q.x), a2); a3 = fdot2(BW(U3,(o)+0), BH(q.x), a3);\
    a4 = fdot2(BW(U4,(o)+0), BH(q.x), a4); a5 = fdot2(BW(U5,(o)+0), BH(q.x), a5);\
    a0 = fdot2(BW(U0,(o)+1), BH(q.y), a0); a1 = fdot2(BW(U1,(o)+1), BH(q.y), a1);\
    a2 = fdot2(BW(U2,(o)+1), BH(q.y), a2); a3 = fdot2(BW(U3,(o)+1), BH(q.y), a3);\
    a4 = fdot2(BW(U4,(o)+1), BH(q.y), a4); a5 = fdot2(BW(U5,(o)+1), BH(q.y), a5);\
    a0 = fdot2(BW(U0,(o)+2), BH(q.z), a0); a1 = fdot2(BW(U1,(o)+2), BH(q.z), a1);\
    a2 = fdot2(BW(U2,(o)+2), BH(q.z), a2); a3 = fdot2(BW(U3,(o)+2), BH(q.z), a3);\
    a4 = fdot2(BW(U4,(o)+2), BH(q.z), a4); a5 = fdot2(BW(U5,(o)+2), BH(q.z), a5);\
    a0 = fdot2(BW(U0,(o)+3), BH(q.w), a0); a1 = fdot2(BW(U1,(o)+3), BH(q.w), a1);\
    a2 = fdot2(BW(U2,(o)+3), BH(q.w), a2); a3 = fdot2(BW(U3,(o)+3), BH(q.w), a3);\
    a4 = fdot2(BW(U4,(o)+3), BH(q.w), a4); a5 = fdot2(BW(U5,(o)+3), BH(q.w), a5);\
  } while (0)

#define LDW(W, o) do {                                                        \
    int4 q0 = wsrc[(o) + 0], q1 = wsrc[(o) + 1];                              \
    int4 q2 = wsrc[(o) + 2], q3 = wsrc[(o) + 3];                              \
    W = (int16v){q0.x, q0.y, q0.z, q0.w, q1.x, q1.y, q1.z, q1.w,              \
                 q2.x, q2.y, q2.z, q2.w, q3.x, q3.y, q3.z, q3.w};             \
  } while (0)

// load 48 int4 of weights into 12 pinned int16v (the R4/R7 pattern: compiles
// and passes; values asm-opaque so loads cannot sink into the loop)
#define LOADPIN_W(SRC) \
  int16v W0a, W0b, W1a, W1b, W2a, W2b, W3a, W3b, W4a, W4b, W5a, W5b;         \
  {                                                                           \
    const int4* wsrc = (const int4*)(SRC);                                    \
    LDW(W0a, 0);  LDW(W0b, 4);  LDW(W1a, 8);  LDW(W1b, 12);                   \
    LDW(W2a, 16); LDW(W2b, 20); LDW(W3a, 24); LDW(W3b, 28);                   \
    LDW(W4a, 32); LDW(W4b, 36); LDW(W5a, 40); LDW(W5b, 44);                   \
  }                                                                           \
  asm volatile("" : "+v"(W0a), "+v"(W0b), "+v"(W1a), "+v"(W1b),               \
                    "+v"(W2a), "+v"(W2b), "+v"(W3a), "+v"(W3b),               \
                    "+v"(W4a), "+v"(W4b), "+v"(W5a), "+v"(W5b));

// 8 chunks of 16B against the full 6-row slice set
#define DOT6x8() do {                                                         \
    DOT6(q0, W0a, W1a, W2a, W3a, W4a, W5a, 0);                                \
    DOT6(q1, W0a, W1a, W2a, W3a, W4a, W5a, 4);                                \
    DOT6(q2, W0a, W1a, W2a, W3a, W4a, W5a, 8);                                \
    DOT6(q3, W0a, W1a, W2a, W3a, W4a, W5a, 12);                               \
    DOT6(q4, W0b, W1b, W2b, W3b, W4b, W5b, 0);                                \
    DOT6(q5, W0b, W1b, W2b, W3b, W4b, W5b, 4);                                \
    DOT6(q6, W0b, W1b, W2b, W3b, W4b, W5b, 8);                                \
    DOT6(q7, W0b, W1b, W2b, W3b, W4b, W5b, 12);                               \
  } while (0)

// parity-early quad reduction: level1 both parities (6 dpp + 6 add), select
// own parity (3 cndmask), level2 same-parity partner (3 dpp + 3 add).
// Tree ((a^c + a^c1) + (a^c2 + a^c3)) identical to the old quad_sum -> bit-
// identical, 6 fewer VALU.
#define QREDUCE(MVR, MVZ, MVN) do {                                           \
    float b0 = a0 + dpp_xor1(a0), b1 = a1 + dpp_xor1(a1);                     \
    float b2 = a2 + dpp_xor1(a2), b3 = a3 + dpp_xor1(a3);                     \
    float b4 = a4 + dpp_xor1(a4), b5 = a5 + dpp_xor1(a5);                     \
    float xr_ = jj ? b1 : b0, xz_ = jj ? b3 : b2, xn_ = jj ? b5 : b4;         \
    MVR = xr_ + dpp_xor2(xr_);                                                \
    MVZ = xz_ + dpp_xor2(xz_);                                                \
    MVN = xn_ + dpp_xor2(xn_);                                                \
  } while (0)

// ---------------- prep: input f32 -> f16 (+ flag init) ----------------
__global__ __launch_bounds__(256) void prep_in_kernel(const float* __restrict__ in,
                                                      _Float16* __restrict__ in16,
                                                      int* __restrict__ flags) {
  size_t v = (size_t)blockIdx.x * 256 + threadIdx.x;
  if (blockIdx.x < 9) {
    int i = blockIdx.x * 256 + threadIdx.x;
    if (i < XPB) flags[i] = 0;
    else if (i < XPB + 8) flags[i] = 1;   // sentinels for blanket 12-wide check
  }
  const float4* p4 = (const float4*)in;
  float4 a = p4[v * 2 + 0];
  float4 b = p4[v * 2 + 1];
  half8_t o;
  o[0] = (_Float16)a.x; o[1] = (_Float16)a.y; o[2] = (_Float16)a.z; o[3] = (_Float16)a.w;
  o[4] = (_Float16)b.x; o[5] = (_Float16)b.y; o[6] = (_Float16)b.z; o[7] = (_Float16)b.w;
  ((half8_t*)in16)[v] = o;
}

// ---------------- prep: weights ----------------
// whh3/wih3 layout (G=6/S=4): thread tid = j1*4+c owns 192 contiguous dwords
// [d][kk], d = gate*2+jj in 0..5, kk in 0..31: half2 of
// W[row = gate*256 + 2*j1 + jj][col = 64*c + 2*kk .. +1].
__global__ __launch_bounds__(256) void prep_w_kernel(const float* __restrict__ W_ih,
                                                     const float* __restrict__ W_hh,
                                                     const float* __restrict__ b_ih,
                                                     const float* __restrict__ b_hh,
                                                     half2_t* __restrict__ whh3,
                                                     half2_t* __restrict__ wih3,
                                                     float* __restrict__ bias) {
  int idx = blockIdx.x * 256 + threadIdx.x;
  if (idx < 128 * NG) {
    int tid = idx / 192;
    int r   = idx - tid * 192;
    int d   = r >> 5, kk = r & 31;
    int gate = d >> 1, jj = d & 1;
    int c  = tid & 3, j1 = tid >> 2;
    int row = gate * NH + 2 * j1 + jj;
    int col = 64 * c + 2 * kk;
    whh3[idx] = pack2(W_hh[(size_t)row * NH + col], W_hh[(size_t)row * NH + col + 1]);
  } else if (idx < 2 * 128 * NG) {
    int i2  = idx - 128 * NG;
    int tid = i2 / 192;
    int r   = i2 - tid * 192;
    int d   = r >> 5, kk = r & 31;
    int gate = d >> 1, jj = d & 1;
    int c  = tid & 3, j1 = tid >> 2;
    int row = gate * NH + 2 * j1 + jj;
    int col = 64 * c + 2 * kk;
    wih3[i2] = pack2(W_ih[(size_t)row * NIN + col], W_ih[(size_t)row * NIN + col + 1]);
  } else if (idx < 2 * 128 * NG + NG) {
    int g = idx - 2 * 128 * NG;
    bias[g] = b_ih[g] + b_hh[g];
  }
}

// ---------------- fused: gru (blocks 0..31) + xproj (blocks 32..2079) -------
// R8 theory: gru (2283us) is within ~15-20% of its fixed per-CU fdot2 issue
// floor (~1536 cyc/step at 4-cyc dot2; unified VGPR/AGPR file means no
// shuttle -- R7 A/B proved operand position irrelevant). The remaining serial
// cost is the ~300us prolog (xproj 250us runs while gru CUs idle, then gru
// runs while 224 CUs idle). Fix: one launch; xproj blocks (1 step's 32 rows
// each, same 512-thr/192-dword engine fed by W_ih) produce xp 8-10x faster
// than gru consumes; per-step flags gate gru's xp prefetch. Release: barrier
// + agent-release flag store (wbl2 -> data at MALL before flag). Consume:
// sc0sc1 12-wide flag loads once per 8 steps; xp data lines are first-touch
// after the flag, so plain cached loads are safe. No deadlock: xproj never
// waits; worst-case dispatch order degrades to serialized (current) timing.
__global__
__attribute__((amdgpu_flat_work_group_size(512, 512), amdgpu_waves_per_eu(2, 2)))
void fused_kernel(const _Float16* __restrict__ in16,
                  const half2_t* __restrict__ wih3,
                  const float* __restrict__ bias,
                  float* __restrict__ xp,
                  const half2_t* __restrict__ whh3,
                  float* __restrict__ out,
                  int* __restrict__ flags) {
  const int tid = threadIdx.x;
  const int c   = tid & 3;        // K-quarter
  const int j1  = tid >> 2;       // j-pair index 0..127
  const int jj  = c & 1;          // owned j parity
  const int jmine = 2 * j1 + jj;

  if (blockIdx.x >= GRUB) {
    // ---------------- xproj role: one time-step (32 rows) ----------------
    const int xb = (int)blockIdx.x - GRUB;
    LOADPIN_W(wih3 + (size_t)tid * 192);
    const float bgr = bias[jmine], bgz = bias[NH + jmine], bgn = bias[2 * NH + jmine];
    const char* inrow = (const char*)(in16 + (size_t)xb * 32 * NIN) + c * 128;
    float* xo = xp + (size_t)xb * 32 * NG + jmine;
    for (int rr = 0; rr < 32; ++rr) {
      float a0 = 0.f, a1 = 0.f, a2 = 0.f, a3 = 0.f, a4 = 0.f, a5 = 0.f;
      int4 q0 = *(const int4*)(inrow +   0), q1 = *(const int4*)(inrow +  16);
      int4 q2 = *(const int4*)(inrow +  32), q3 = *(const int4*)(inrow +  48);
      int4 q4 = *(const int4*)(inrow +  64), q5 = *(const int4*)(inrow +  80);
      int4 q6 = *(const int4*)(inrow +  96), q7 = *(const int4*)(inrow + 112);
      DOT6x8();
      float mvr, mvz, mvn;
      QREDUCE(mvr, mvz, mvn);
      if (c < 2) {
        xo[0]      = mvr + bgr;
        xo[NH]     = mvz + bgz;
        xo[2 * NH] = mvn + bgn;
      }
      inrow += NIN * 2;
      xo += NG;
    }
    __syncthreads();   // every wave drains vmcnt(0) -> all xp stores in L2
    if (tid == 0)      // agent-release: wbl2 flush, then device-visible flag
      __hip_atomic_store(&flags[xb], 1, __ATOMIC_RELEASE, __HIP_MEMORY_SCOPE_AGENT);
    return;
  }

  // ---------------- gru role: one batch chain ----------------
  const int b = blockIdx.x;
  LOADPIN_W(whh3 + (size_t)tid * 192);

  // 2 buffers x 4 chunks x 144 B (chunk = 64 f16 + 16 B pad) = 1152 B
  __shared__ __attribute__((aligned(16))) char smh[1152];
  if (tid < 288) ((int*)smh)[tid] = 0;

  FLAGWAIT(flags);   // rows 0..11 ready (covers preload + chunk t0=0)

  const float* xq = xp + (size_t)b * NG + jmine;
  float xr_c = xq[0], xz_c = xq[NH], xn_c = xq[2 * NH];
  xq += (size_t)BATCH * NG;
  float* op = out + (size_t)b * NH + jmine;

  const int wofs = 144 * (jmine >> 6) + 2 * (jmine & 63);

  float h = 0.f;
  __syncthreads();

#define GSTEP(RB, WB) do {                                                    \
    float xr_n = xq[0], xz_n = xq[NH], xn_n = xq[2 * NH];                     \
    const char* hb = smh + (RB) + c * 144;                                    \
    float a0 = 0.f, a1 = 0.f, a2 = 0.f, a3 = 0.f, a4 = 0.f, a5 = 0.f;        \
    int4 q0 = *(const int4*)(hb +   0), q1 = *(const int4*)(hb +  16);       \
    int4 q2 = *(const int4*)(hb +  32), q3 = *(const int4*)(hb +  48);       \
    int4 q4 = *(const int4*)(hb +  64), q5 = *(const int4*)(hb +  80);       \
    int4 q6 = *(const int4*)(hb +  96), q7 = *(const int4*)(hb + 112);       \
    DOT6x8();                                                                 \
    float mvr, mvz, mvn;                                                      \
    QREDUCE(mvr, mvz, mvn);                                                   \
    float r = sigmoid_fast(xr_c + mvr);                                       \
    float z = sigmoid_fast(xz_c + mvz);                                       \
    float n = tanh_fast(xn_c + mvn + r * mvn);  /* torch quirk */            \
    h = z * (h - n) + n;                                                      \
    if (c < 2) {                                                              \
      op[0] = h;                                                              \
      *(_Float16*)(smh + (WB) + wofs) = (_Float16)h;                          \
    }                                                                         \
    asm volatile("s_waitcnt lgkmcnt(0)\n\ts_barrier" ::: "memory");           \
    xr_c = xr_n; xz_c = xz_n; xn_c = xn_n;                                    \
    xq += (size_t)BATCH * NG;                                                 \
    op += (size_t)BATCH * NH;                                                 \
  } while (0)

  for (int t0 = 0; t0 < S_LEN; t0 += 8) {
    if (t0) FLAGWAIT(flags + t0);   // rows t0..t0+11 >= needed t0+1..t0+8
    for (int u = 0; u < 4; ++u) {
      GSTEP(0, 576);
      GSTEP(576, 0);
    }
  }
#undef GSTEP

  if (c < 2) out[(size_t)S_LEN * BATCH * NH + (size_t)b * NH + jmine] = h;
}

extern "C" void kernel_launch(void* const* d_in, const int* in_sizes, int n_in,
                              void* d_out, int out_size, void* d_ws, size_t ws_size,
                              hipStream_t stream) {
  const float* input = (const float*)d_in[0];
  const float* W_ih  = (const float*)d_in[1];
  const float* W_hh  = (const float*)d_in[2];
  const float* b_ih  = (const float*)d_in[3];
  const float* b_hh  = (const float*)d_in[4];
  float* out = (float*)d_out;

  const size_t SB = (size_t)S_LEN * BATCH;           // 65536
  const size_t xp_b   = SB * NG * 4;                 // 192 MiB
  const size_t in16_b = SB * NIN * 2;                // 32 MiB
  const size_t w_b    = (size_t)128 * NG * 4;        // 384 KiB each

  char* p = (char*)d_ws;
  float*    xp    = (float*)p;                p += xp_b;
  _Float16* in16  = (_Float16*)p;             p += in16_b;
  half2_t*  whh3  = (half2_t*)p;              p += w_b;
  half2_t*  wih3  = (half2_t*)p;              p += w_b;
  float*    bias  = (float*)p;                p += (size_t)NG * 4;
  uintptr_t fp_ = (((uintptr_t)p) + 127) & ~(uintptr_t)127;
  int*      flags = (int*)fp_;                // 2056 ints (2048 + sentinels)

  prep_in_kernel<<<8192, 256, 0, stream>>>(input, in16, flags);
  prep_w_kernel<<<(2 * 128 * NG + NG + 255) / 256, 256, 0, stream>>>(W_ih, W_hh, b_ih, b_hh,
                                                                     whh3, wih3, bias);
  fused_kernel<<<GRUB + XPB, 512, 0, stream>>>(in16, wih3, bias, xp, whh3, out, flags);
  (void)out_size; (void)n_in; (void)in_sizes; (void)ws_size;
}

// Round 9
// 2348.770 us; speedup vs baseline: 1.1185x; 1.0057x over previous
//
#include <hip/hip_runtime.h>
#include <stdint.h>
#include <stddef.h>

#define S_LEN 2048
#define BATCH 32
#define NIN   256
#define NH    256
#define NG    768   // 3*NH
#define GRUB  32    // gru role blocks
#define XPB   2048  // xproj role blocks (32 rows = 1 step each)

typedef _Float16 half2_t __attribute__((ext_vector_type(2)));
typedef int      int16v  __attribute__((ext_vector_type(16)));
typedef int      int4v   __attribute__((ext_vector_type(4)));

#if __has_builtin(__builtin_amdgcn_exp2f)
#define EXP2F(x) __builtin_amdgcn_exp2f(x)
#else
#define EXP2F(x) exp2f(x)
#endif

static __device__ __forceinline__ float fdot2(half2_t a, half2_t b, float c) {
  return __builtin_amdgcn_fdot2(a, b, c, false);
}
static __device__ __forceinline__ half2_t pack2(float lo, float hi) {
  half2_t r; r[0] = (_Float16)lo; r[1] = (_Float16)hi; return r;
}
static __device__ __forceinline__ float sigmoid_fast(float x) {
  float e = EXP2F(-1.44269504088896340736f * x);
  return 1.0f / (1.0f + e);
}
static __device__ __forceinline__ float tanh_fast(float x) {
  float e = EXP2F(2.88539008177792681472f * x);
  return 1.0f - 2.0f / (1.0f + e);
}
static __device__ __forceinline__ float dpp_xor1(float v) {
  return __builtin_bit_cast(float,
    __builtin_amdgcn_mov_dpp(__builtin_bit_cast(int, v), 0xB1, 0xF, 0xF, true));
}
static __device__ __forceinline__ float dpp_xor2(float v) {
  return __builtin_bit_cast(float,
    __builtin_amdgcn_mov_dpp(__builtin_bit_cast(int, v), 0x4E, 0xF, 0xF, true));
}

// 36 ready-flags in one shot, device-coherent (sc0 sc1 bypasses L1+XCD-L2),
// single base + literal offsets, ONE vmcnt(0) drain per poll.
static __device__ __forceinline__ int flags_all36(const int* p) {
  int4v a0, a1, a2, a3, a4, a5, a6, a7, a8;
  asm volatile("global_load_dwordx4 %0, %9, off sc0 sc1\n"
               "global_load_dwordx4 %1, %9, off offset:16 sc0 sc1\n"
               "global_load_dwordx4 %2, %9, off offset:32 sc0 sc1\n"
               "global_load_dwordx4 %3, %9, off offset:48 sc0 sc1\n"
               "global_load_dwordx4 %4, %9, off offset:64 sc0 sc1\n"
               "global_load_dwordx4 %5, %9, off offset:80 sc0 sc1\n"
               "global_load_dwordx4 %6, %9, off offset:96 sc0 sc1\n"
               "global_load_dwordx4 %7, %9, off offset:112 sc0 sc1\n"
               "global_load_dwordx4 %8, %9, off offset:128 sc0 sc1\n"
               "s_waitcnt vmcnt(0)"
               : "=v"(a0), "=v"(a1), "=v"(a2), "=v"(a3), "=v"(a4),
                 "=v"(a5), "=v"(a6), "=v"(a7), "=v"(a8)
               : "v"(p)
               : "memory");
  int all = a0.x & a0.y & a0.z & a0.w;
  all &= a1.x & a1.y & a1.z & a1.w;
  all &= a2.x & a2.y & a2.z & a2.w;
  all &= a3.x & a3.y & a3.z & a3.w;
  all &= a4.x & a4.y & a4.z & a4.w;
  all &= a5.x & a5.y & a5.z & a5.w;
  all &= a6.x & a6.y & a6.z & a6.w;
  all &= a7.x & a7.y & a7.z & a7.w;
  all &= a8.x & a8.y & a8.z & a8.w;
  return all;
}
#define FLAGWAIT36(BASEP) do {                                                \
    while (!flags_all36(BASEP)) __builtin_amdgcn_s_sleep(16);                 \
  } while (0)

// bit-cast helpers: element extracts use LITERAL indices -> pure SSA
#define BH(x)    __builtin_bit_cast(half2_t, (x))
#define BW(W, e) __builtin_bit_cast(half2_t, (int)((W)[e]))
#define P2I(a, b) __builtin_bit_cast(int, pack2((a), (b)))

// one 16B operand chunk (4 half2) against 6 row-slices (2j x 3 gates).
// Weight as src0. Accumulator reuse distance 6 -> no VALU dep stalls.
#define DOT6(q, U0, U1, U2, U3, U4, U5, o) do {                               \
    a0 = fdot2(BW(U0,(o)+0), BH(q.x), a0); a1 = fdot2(BW(U1,(o)+0), BH(q.x), a1);\
    a2 = fdot2(BW(U2,(o)+0), BH(q.x), a2); a3 = fdot2(BW(U3,(o)+0), BH(q.x), a3);\
    a4 = fdot2(BW(U4,(o)+0), BH(q.x), a4); a5 = fdot2(BW(U5,(o)+0), BH(q.x), a5);\
    a0 = fdot2(BW(U0,(o)+1), BH(q.y), a0); a1 = fdot2(BW(U1,(o)+1), BH(q.y), a1);\
    a2 = fdot2(BW(U2,(o)+1), BH(q.y), a2); a3 = fdot2(BW(U3,(o)+1), BH(q.y), a3);\
    a4 = fdot2(BW(U4,(o)+1), BH(q.y), a4); a5 = fdot2(BW(U5,(o)+1), BH(q.y), a5);\
    a0 = fdot2(BW(U0,(o)+2), BH(q.z), a0); a1 = fdot2(BW(U1,(o)+2), BH(q.z), a1);\
    a2 = fdot2(BW(U2,(o)+2), BH(q.z), a2); a3 = fdot2(BW(U3,(o)+2), BH(q.z), a3);\
    a4 = fdot2(BW(U4,(o)+2), BH(q.z), a4); a5 = fdot2(BW(U5,(o)+2), BH(q.z), a5);\
    a0 = fdot2(BW(U0,(o)+3), BH(q.w), a0); a1 = fdot2(BW(U1,(o)+3), BH(q.w), a1);\
    a2 = fdot2(BW(U2,(o)+3), BH(q.w), a2); a3 = fdot2(BW(U3,(o)+3), BH(q.w), a3);\
    a4 = fdot2(BW(U4,(o)+3), BH(q.w), a4); a5 = fdot2(BW(U5,(o)+3), BH(q.w), a5);\
  } while (0)

#define LDW(W, o) do {                                                        \
    int4 q0 = wsrc[(o) + 0], q1 = wsrc[(o) + 1];                              \
    int4 q2 = wsrc[(o) + 2], q3 = wsrc[(o) + 3];                              \
    W = (int16v){q0.x, q0.y, q0.z, q0.w, q1.x, q1.y, q1.z, q1.w,              \
                 q2.x, q2.y, q2.z, q2.w, q3.x, q3.y, q3.z, q3.w};             \
  } while (0)

// load 48 int4 of weights into 12 pinned int16v (R4/R7 pattern: compiles and
// passes; values asm-opaque so loads cannot sink into the loop)
#define LOADPIN_W(SRC) \
  int16v W0a, W0b, W1a, W1b, W2a, W2b, W3a, W3b, W4a, W4b, W5a, W5b;         \
  {                                                                           \
    const int4* wsrc = (const int4*)(SRC);                                    \
    LDW(W0a, 0);  LDW(W0b, 4);  LDW(W1a, 8);  LDW(W1b, 12);                   \
    LDW(W2a, 16); LDW(W2b, 20); LDW(W3a, 24); LDW(W3b, 28);                   \
    LDW(W4a, 32); LDW(W4b, 36); LDW(W5a, 40); LDW(W5b, 44);                   \
  }                                                                           \
  asm volatile("" : "+v"(W0a), "+v"(W0b), "+v"(W1a), "+v"(W1b),               \
                    "+v"(W2a), "+v"(W2b), "+v"(W3a), "+v"(W3b),               \
                    "+v"(W4a), "+v"(W4b), "+v"(W5a), "+v"(W5b));

// 8 chunks of 16B against the full 6-row slice set (gru path)
#define DOT6x8() do {                                                         \
    DOT6(q0, W0a, W1a, W2a, W3a, W4a, W5a, 0);                                \
    DOT6(q1, W0a, W1a, W2a, W3a, W4a, W5a, 4);                                \
    DOT6(q2, W0a, W1a, W2a, W3a, W4a, W5a, 8);                                \
    DOT6(q3, W0a, W1a, W2a, W3a, W4a, W5a, 12);                               \
    DOT6(q4, W0b, W1b, W2b, W3b, W4b, W5b, 0);                                \
    DOT6(q5, W0b, W1b, W2b, W3b, W4b, W5b, 4);                                \
    DOT6(q6, W0b, W1b, W2b, W3b, W4b, W5b, 8);                                \
    DOT6(q7, W0b, W1b, W2b, W3b, W4b, W5b, 12);                               \
  } while (0)

// parity-early quad reduction (bit-identical to quad_sum tree, 6 fewer VALU)
#define QREDUCE(MVR, MVZ, MVN) do {                                           \
    float b0 = a0 + dpp_xor1(a0), b1 = a1 + dpp_xor1(a1);                     \
    float b2 = a2 + dpp_xor1(a2), b3 = a3 + dpp_xor1(a3);                     \
    float b4 = a4 + dpp_xor1(a4), b5 = a5 + dpp_xor1(a5);                     \
    float xr_ = jj ? b1 : b0, xz_ = jj ? b3 : b2, xn_ = jj ? b5 : b4;         \
    MVR = xr_ + dpp_xor2(xr_);                                                \
    MVZ = xz_ + dpp_xor2(xz_);                                                \
    MVN = xn_ + dpp_xor2(xn_);                                                \
  } while (0)

// ---------------- prep: weights + flag init ----------------
// whh3/wih3 layout (G=6/S=4): thread tid = j1*4+c owns 192 contiguous dwords
// [d][kk], d = gate*2+jj in 0..5, kk in 0..31: half2 of
// W[row = gate*256 + 2*j1 + jj][col = 64*c + 2*kk .. +1].
__global__ __launch_bounds__(256) void prep_w_kernel(const float* __restrict__ W_ih,
                                                     const float* __restrict__ W_hh,
                                                     const float* __restrict__ b_ih,
                                                     const float* __restrict__ b_hh,
                                                     half2_t* __restrict__ whh3,
                                                     half2_t* __restrict__ wih3,
                                                     float* __restrict__ bias,
                                                     int* __restrict__ flags) {
  int idx = blockIdx.x * 256 + threadIdx.x;
  if (idx < 128 * NG) {
    int tid = idx / 192;
    int r   = idx - tid * 192;
    int d   = r >> 5, kk = r & 31;
    int gate = d >> 1, jj = d & 1;
    int c  = tid & 3, j1 = tid >> 2;
    int row = gate * NH + 2 * j1 + jj;
    int col = 64 * c + 2 * kk;
    whh3[idx] = pack2(W_hh[(size_t)row * NH + col], W_hh[(size_t)row * NH + col + 1]);
  } else if (idx < 2 * 128 * NG) {
    int i2  = idx - 128 * NG;
    int tid = i2 / 192;
    int r   = i2 - tid * 192;
    int d   = r >> 5, kk = r & 31;
    int gate = d >> 1, jj = d & 1;
    int c  = tid & 3, j1 = tid >> 2;
    int row = gate * NH + 2 * j1 + jj;
    int col = 64 * c + 2 * kk;
    wih3[i2] = pack2(W_ih[(size_t)row * NIN + col], W_ih[(size_t)row * NIN + col + 1]);
  } else if (idx < 2 * 128 * NG + NG) {
    int g = idx - 2 * 128 * NG;
    bias[g] = b_ih[g] + b_hh[g];
  } else if (idx < 2 * 128 * NG + NG + XPB + 16) {
    int k = idx - (2 * 128 * NG + NG);
    flags[k] = (k < XPB) ? 0 : 1;   // 16 sentinels for the 36-wide check
  }
}

// ---------------- fused: gru (blocks 0..31) + xproj (blocks 32..2079) -------
// R9: R8 matched (overlap works; 1 block/CU via waves_per_eu(2,2) rules out
// CU sharing). Fused-vs-standalone delta = +117 cyc/step attributed to the
// per-8-step poll (MALL roundtrip + vmcnt(0) drain vs in-flight out stores).
// Changes: (1) poll per 32 steps, 9-load/1-drain 36-wide check (~25 cyc/step);
// (2) xproj converts f32 input in-register (RNE pack2, bit-identical to the
// deleted prep_in) -- input rows are private per xproj block, no sharing.
__global__
__attribute__((amdgpu_flat_work_group_size(512, 512), amdgpu_waves_per_eu(2, 2)))
void fused_kernel(const float* __restrict__ inf,
                  const half2_t* __restrict__ wih3,
                  const float* __restrict__ bias,
                  float* __restrict__ xp,
                  const half2_t* __restrict__ whh3,
                  float* __restrict__ out,
                  int* __restrict__ flags) {
  const int tid = threadIdx.x;
  const int c   = tid & 3;        // K-quarter
  const int j1  = tid >> 2;       // j-pair index 0..127
  const int jj  = c & 1;          // owned j parity
  const int jmine = 2 * j1 + jj;

  if (blockIdx.x >= GRUB) {
    // ---------------- xproj role: one time-step (32 rows) ----------------
    const int xb = (int)blockIdx.x - GRUB;
    LOADPIN_W(wih3 + (size_t)tid * 192);
    const float bgr = bias[jmine], bgz = bias[NH + jmine], bgn = bias[2 * NH + jmine];
    const float4* fr = (const float4*)(inf + (size_t)xb * 32 * NIN + c * 64);
    float* xo = xp + (size_t)xb * 32 * NG + jmine;
    for (int rr = 0; rr < 32; ++rr) {
      float a0 = 0.f, a1 = 0.f, a2 = 0.f, a3 = 0.f, a4 = 0.f, a5 = 0.f;
      float4 g0, g1; int4 q;
#define XB(IDX, U0, U1, U2, U3, U4, U5, OFF)                                  \
      g0 = fr[2 * (IDX)]; g1 = fr[2 * (IDX) + 1];                             \
      q.x = P2I(g0.x, g0.y); q.y = P2I(g0.z, g0.w);                           \
      q.z = P2I(g1.x, g1.y); q.w = P2I(g1.z, g1.w);                           \
      DOT6(q, U0, U1, U2, U3, U4, U5, OFF);
      XB(0, W0a, W1a, W2a, W3a, W4a, W5a, 0)
      XB(1, W0a, W1a, W2a, W3a, W4a, W5a, 4)
      XB(2, W0a, W1a, W2a, W3a, W4a, W5a, 8)
      XB(3, W0a, W1a, W2a, W3a, W4a, W5a, 12)
      XB(4, W0b, W1b, W2b, W3b, W4b, W5b, 0)
      XB(5, W0b, W1b, W2b, W3b, W4b, W5b, 4)
      XB(6, W0b, W1b, W2b, W3b, W4b, W5b, 8)
      XB(7, W0b, W1b, W2b, W3b, W4b, W5b, 12)
#undef XB
      float mvr, mvz, mvn;
      QREDUCE(mvr, mvz, mvn);
      if (c < 2) {
        xo[0]      = mvr + bgr;
        xo[NH]     = mvz + bgz;
        xo[2 * NH] = mvn + bgn;
      }
      fr += 64;   // next row (256 floats)
      xo += NG;
    }
    __syncthreads();   // every wave drains vmcnt(0) -> all xp stores in L2
    if (tid == 0)      // agent-release: data visible before flag
      __hip_atomic_store(&flags[xb], 1, __ATOMIC_RELEASE, __HIP_MEMORY_SCOPE_AGENT);
    return;
  }

  // ---------------- gru role: one batch chain ----------------
  const int b = blockIdx.x;
  LOADPIN_W(whh3 + (size_t)tid * 192);

  // 2 buffers x 4 chunks x 144 B (chunk = 64 f16 + 16 B pad) = 1152 B
  __shared__ __attribute__((aligned(16))) char smh[1152];
  if (tid < 288) ((int*)smh)[tid] = 0;

  FLAGWAIT36(flags);   // rows 0..35 ready: covers preload + window-0 prefetches

  const float* xq = xp + (size_t)b * NG + jmine;
  float xr_c = xq[0], xz_c = xq[NH], xn_c = xq[2 * NH];
  xq += (size_t)BATCH * NG;
  float* op = out + (size_t)b * NH + jmine;

  const int wofs = 144 * (jmine >> 6) + 2 * (jmine & 63);

  float h = 0.f;
  __syncthreads();

#define GSTEP(RB, WB) do {                                                    \
    float xr_n = xq[0], xz_n = xq[NH], xn_n = xq[2 * NH];                     \
    const char* hb = smh + (RB) + c * 144;                                    \
    float a0 = 0.f, a1 = 0.f, a2 = 0.f, a3 = 0.f, a4 = 0.f, a5 = 0.f;        \
    int4 q0 = *(const int4*)(hb +   0), q1 = *(const int4*)(hb +  16);       \
    int4 q2 = *(const int4*)(hb +  32), q3 = *(const int4*)(hb +  48);       \
    int4 q4 = *(const int4*)(hb +  64), q5 = *(const int4*)(hb +  80);       \
    int4 q6 = *(const int4*)(hb +  96), q7 = *(const int4*)(hb + 112);       \
    DOT6x8();                                                                 \
    float mvr, mvz, mvn;                                                      \
    QREDUCE(mvr, mvz, mvn);                                                   \
    float r = sigmoid_fast(xr_c + mvr);                                       \
    float z = sigmoid_fast(xz_c + mvz);                                       \
    float n = tanh_fast(xn_c + mvn + r * mvn);  /* torch quirk */            \
    h = z * (h - n) + n;                                                      \
    if (c < 2) {                                                              \
      op[0] = h;                                                              \
      *(_Float16*)(smh + (WB) + wofs) = (_Float16)h;                          \
    }                                                                         \
    asm volatile("s_waitcnt lgkmcnt(0)\n\ts_barrier" ::: "memory");           \
    xr_c = xr_n; xz_c = xz_n; xn_c = xn_n;                                    \
    xq += (size_t)BATCH * NG;                                                 \
    op += (size_t)BATCH * NH;                                                 \
  } while (0)

  for (int t0 = 0; t0 < S_LEN; t0 += 8) {
    if (t0 && (t0 & 31) == 0) FLAGWAIT36(flags + t0);  // rows t0..t0+35
    for (int u = 0; u < 4; ++u) {
      GSTEP(0, 576);
      GSTEP(576, 0);
    }
  }
#undef GSTEP

  if (c < 2) out[(size_t)S_LEN * BATCH * NH + (size_t)b * NH + jmine] = h;
}

extern "C" void kernel_launch(void* const* d_in, const int* in_sizes, int n_in,
                              void* d_out, int out_size, void* d_ws, size_t ws_size,
                              hipStream_t stream) {
  const float* input = (const float*)d_in[0];
  const float* W_ih  = (const float*)d_in[1];
  const float* W_hh  = (const float*)d_in[2];
  const float* b_ih  = (const float*)d_in[3];
  const float* b_hh  = (const float*)d_in[4];
  float* out = (float*)d_out;

  const size_t SB = (size_t)S_LEN * BATCH;           // 65536
  const size_t xp_b = SB * NG * 4;                   // 192 MiB
  const size_t w_b  = (size_t)128 * NG * 4;          // 384 KiB each

  char* p = (char*)d_ws;
  float*    xp    = (float*)p;                p += xp_b;
  half2_t*  whh3  = (half2_t*)p;              p += w_b;
  half2_t*  wih3  = (half2_t*)p;              p += w_b;
  float*    bias  = (float*)p;                p += (size_t)NG * 4;
  uintptr_t fp_ = (((uintptr_t)p) + 127) & ~(uintptr_t)127;
  int*      flags = (int*)fp_;                // 2064 ints (2048 + 16 sentinels)

  const int prep_items = 2 * 128 * NG + NG + XPB + 16;
  prep_w_kernel<<<(prep_items + 255) / 256, 256, 0, stream>>>(W_ih, W_hh, b_ih, b_hh,
                                                              whh3, wih3, bias, flags);
  fused_kernel<<<GRUB + XPB, 512, 0, stream>>>(input, wih3, bias, xp, whh3, out, flags);
  (void)out_size; (void)n_in; (void)in_sizes; (void)ws_size;
}

// Round 10
// 2332.722 us; speedup vs baseline: 1.1262x; 1.0069x over previous
//
#include <hip/hip_runtime.h>
#include <stdint.h>
#include <stddef.h>

#define S_LEN 2048
#define BATCH 32
#define NIN   256
#define NH    256
#define NG    768   // 3*NH
#define GRUB  32    // gru role blocks
#define XPB   2048  // xproj role blocks (32 rows = 1 step each)

typedef _Float16 half2_t __attribute__((ext_vector_type(2)));
typedef int      int16v  __attribute__((ext_vector_type(16)));
typedef int      int4v   __attribute__((ext_vector_type(4)));

#if __has_builtin(__builtin_amdgcn_exp2f)
#define EXP2F(x) __builtin_amdgcn_exp2f(x)
#else
#define EXP2F(x) exp2f(x)
#endif

static __device__ __forceinline__ float fdot2(half2_t a, half2_t b, float c) {
  return __builtin_amdgcn_fdot2(a, b, c, false);
}
static __device__ __forceinline__ half2_t pack2(float lo, float hi) {
  half2_t r; r[0] = (_Float16)lo; r[1] = (_Float16)hi; return r;
}
static __device__ __forceinline__ float sigmoid_fast(float x) {
  float e = EXP2F(-1.44269504088896340736f * x);
  return 1.0f / (1.0f + e);
}
static __device__ __forceinline__ float tanh_fast(float x) {
  float e = EXP2F(2.88539008177792681472f * x);
  return 1.0f - 2.0f / (1.0f + e);
}
static __device__ __forceinline__ float dpp_xor1(float v) {
  return __builtin_bit_cast(float,
    __builtin_amdgcn_mov_dpp(__builtin_bit_cast(int, v), 0xB1, 0xF, 0xF, true));
}
static __device__ __forceinline__ float dpp_xor2(float v) {
  return __builtin_bit_cast(float,
    __builtin_amdgcn_mov_dpp(__builtin_bit_cast(int, v), 0x4E, 0xF, 0xF, true));
}

// 36 ready-flags in one shot, device-coherent (sc0 sc1 bypasses L1+XCD-L2),
// single base + literal offsets, ONE vmcnt(0) drain per poll.
static __device__ __forceinline__ int flags_all36(const int* p) {
  int4v a0, a1, a2, a3, a4, a5, a6, a7, a8;
  asm volatile("global_load_dwordx4 %0, %9, off sc0 sc1\n"
               "global_load_dwordx4 %1, %9, off offset:16 sc0 sc1\n"
               "global_load_dwordx4 %2, %9, off offset:32 sc0 sc1\n"
               "global_load_dwordx4 %3, %9, off offset:48 sc0 sc1\n"
               "global_load_dwordx4 %4, %9, off offset:64 sc0 sc1\n"
               "global_load_dwordx4 %5, %9, off offset:80 sc0 sc1\n"
               "global_load_dwordx4 %6, %9, off offset:96 sc0 sc1\n"
               "global_load_dwordx4 %7, %9, off offset:112 sc0 sc1\n"
               "global_load_dwordx4 %8, %9, off offset:128 sc0 sc1\n"
               "s_waitcnt vmcnt(0)"
               : "=v"(a0), "=v"(a1), "=v"(a2), "=v"(a3), "=v"(a4),
                 "=v"(a5), "=v"(a6), "=v"(a7), "=v"(a8)
               : "v"(p)
               : "memory");
  int all = a0.x & a0.y & a0.z & a0.w;
  all &= a1.x & a1.y & a1.z & a1.w;
  all &= a2.x & a2.y & a2.z & a2.w;
  all &= a3.x & a3.y & a3.z & a3.w;
  all &= a4.x & a4.y & a4.z & a4.w;
  all &= a5.x & a5.y & a5.z & a5.w;
  all &= a6.x & a6.y & a6.z & a6.w;
  all &= a7.x & a7.y & a7.z & a7.w;
  all &= a8.x & a8.y & a8.z & a8.w;
  return all;
}
#define FLAGWAIT36(BASEP) do {                                                \
    while (!flags_all36(BASEP)) __builtin_amdgcn_s_sleep(16);                 \
  } while (0)

// bit-cast helpers: element extracts use LITERAL indices -> pure SSA
#define BH(x)    __builtin_bit_cast(half2_t, (x))
#define BW(W, e) __builtin_bit_cast(half2_t, (int)((W)[e]))
#define P2I(a, b) __builtin_bit_cast(int, pack2((a), (b)))

// one 16B operand chunk (4 half2) against 6 row-slices (2j x 3 gates).
// Weight as src0. Accumulator reuse distance 6 -> no VALU dep stalls.
#define DOT6(q, U0, U1, U2, U3, U4, U5, o) do {                               \
    a0 = fdot2(BW(U0,(o)+0), BH(q.x), a0); a1 = fdot2(BW(U1,(o)+0), BH(q.x), a1);\
    a2 = fdot2(BW(U2,(o)+0), BH(q.x), a2); a3 = fdot2(BW(U3,(o)+0), BH(q.x), a3);\
    a4 = fdot2(BW(U4,(o)+0), BH(q.x), a4); a5 = fdot2(BW(U5,(o)+0), BH(q.x), a5);\
    a0 = fdot2(BW(U0,(o)+1), BH(q.y), a0); a1 = fdot2(BW(U1,(o)+1), BH(q.y), a1);\
    a2 = fdot2(BW(U2,(o)+1), BH(q.y), a2); a3 = fdot2(BW(U3,(o)+1), BH(q.y), a3);\
    a4 = fdot2(BW(U4,(o)+1), BH(q.y), a4); a5 = fdot2(BW(U5,(o)+1), BH(q.y), a5);\
    a0 = fdot2(BW(U0,(o)+2), BH(q.z), a0); a1 = fdot2(BW(U1,(o)+2), BH(q.z), a1);\
    a2 = fdot2(BW(U2,(o)+2), BH(q.z), a2); a3 = fdot2(BW(U3,(o)+2), BH(q.z), a3);\
    a4 = fdot2(BW(U4,(o)+2), BH(q.z), a4); a5 = fdot2(BW(U5,(o)+2), BH(q.z), a5);\
    a0 = fdot2(BW(U0,(o)+3), BH(q.w), a0); a1 = fdot2(BW(U1,(o)+3), BH(q.w), a1);\
    a2 = fdot2(BW(U2,(o)+3), BH(q.w), a2); a3 = fdot2(BW(U3,(o)+3), BH(q.w), a3);\
    a4 = fdot2(BW(U4,(o)+3), BH(q.w), a4); a5 = fdot2(BW(U5,(o)+3), BH(q.w), a5);\
  } while (0)

#define LDW(W, o) do {                                                        \
    int4 q0 = wsrc[(o) + 0], q1 = wsrc[(o) + 1];                              \
    int4 q2 = wsrc[(o) + 2], q3 = wsrc[(o) + 3];                              \
    W = (int16v){q0.x, q0.y, q0.z, q0.w, q1.x, q1.y, q1.z, q1.w,              \
                 q2.x, q2.y, q2.z, q2.w, q3.x, q3.y, q3.z, q3.w};             \
  } while (0)

// load 48 int4 of weights into 12 pinned int16v (R4/R7 pattern: compiles and
// passes; values asm-opaque so loads cannot sink into the loop)
#define LOADPIN_W(SRC) \
  int16v W0a, W0b, W1a, W1b, W2a, W2b, W3a, W3b, W4a, W4b, W5a, W5b;         \
  {                                                                           \
    const int4* wsrc = (const int4*)(SRC);                                    \
    LDW(W0a, 0);  LDW(W0b, 4);  LDW(W1a, 8);  LDW(W1b, 12);                   \
    LDW(W2a, 16); LDW(W2b, 20); LDW(W3a, 24); LDW(W3b, 28);                   \
    LDW(W4a, 32); LDW(W4b, 36); LDW(W5a, 40); LDW(W5b, 44);                   \
  }                                                                           \
  asm volatile("" : "+v"(W0a), "+v"(W0b), "+v"(W1a), "+v"(W1b),               \
                    "+v"(W2a), "+v"(W2b), "+v"(W3a), "+v"(W3b),               \
                    "+v"(W4a), "+v"(W4b), "+v"(W5a), "+v"(W5b));

// 8 chunks of 16B against the full 6-row slice set (gru path)
#define DOT6x8() do {                                                         \
    DOT6(q0, W0a, W1a, W2a, W3a, W4a, W5a, 0);                                \
    DOT6(q1, W0a, W1a, W2a, W3a, W4a, W5a, 4);                                \
    DOT6(q2, W0a, W1a, W2a, W3a, W4a, W5a, 8);                                \
    DOT6(q3, W0a, W1a, W2a, W3a, W4a, W5a, 12);                               \
    DOT6(q4, W0b, W1b, W2b, W3b, W4b, W5b, 0);                                \
    DOT6(q5, W0b, W1b, W2b, W3b, W4b, W5b, 4);                                \
    DOT6(q6, W0b, W1b, W2b, W3b, W4b, W5b, 8);                                \
    DOT6(q7, W0b, W1b, W2b, W3b, W4b, W5b, 12);                               \
  } while (0)

// parity-early quad reduction (bit-identical to quad_sum tree, 6 fewer VALU)
#define QREDUCE(MVR, MVZ, MVN) do {                                           \
    float b0 = a0 + dpp_xor1(a0), b1 = a1 + dpp_xor1(a1);                     \
    float b2 = a2 + dpp_xor1(a2), b3 = a3 + dpp_xor1(a3);                     \
    float b4 = a4 + dpp_xor1(a4), b5 = a5 + dpp_xor1(a5);                     \
    float xr_ = jj ? b1 : b0, xz_ = jj ? b3 : b2, xn_ = jj ? b5 : b4;         \
    MVR = xr_ + dpp_xor2(xr_);                                                \
    MVZ = xz_ + dpp_xor2(xz_);                                                \
    MVN = xn_ + dpp_xor2(xn_);                                                \
  } while (0)

// ---------------- prep: weights + flag init ----------------
// whh3/wih3 layout (G=6/S=4): thread tid = j1*4+c owns 192 contiguous dwords
// [d][kk], d = gate*2+jj in 0..5, kk in 0..31: half2 of
// W[row = gate*256 + 2*j1 + jj][col = 64*c + 2*kk .. +1].
__global__ __launch_bounds__(256) void prep_w_kernel(const float* __restrict__ W_ih,
                                                     const float* __restrict__ W_hh,
                                                     const float* __restrict__ b_ih,
                                                     const float* __restrict__ b_hh,
                                                     half2_t* __restrict__ whh3,
                                                     half2_t* __restrict__ wih3,
                                                     float* __restrict__ bias,
                                                     int* __restrict__ flags) {
  int idx = blockIdx.x * 256 + threadIdx.x;
  if (idx < 128 * NG) {
    int tid = idx / 192;
    int r   = idx - tid * 192;
    int d   = r >> 5, kk = r & 31;
    int gate = d >> 1, jj = d & 1;
    int c  = tid & 3, j1 = tid >> 2;
    int row = gate * NH + 2 * j1 + jj;
    int col = 64 * c + 2 * kk;
    whh3[idx] = pack2(W_hh[(size_t)row * NH + col], W_hh[(size_t)row * NH + col + 1]);
  } else if (idx < 2 * 128 * NG) {
    int i2  = idx - 128 * NG;
    int tid = i2 / 192;
    int r   = i2 - tid * 192;
    int d   = r >> 5, kk = r & 31;
    int gate = d >> 1, jj = d & 1;
    int c  = tid & 3, j1 = tid >> 2;
    int row = gate * NH + 2 * j1 + jj;
    int col = 64 * c + 2 * kk;
    wih3[i2] = pack2(W_ih[(size_t)row * NIN + col], W_ih[(size_t)row * NIN + col + 1]);
  } else if (idx < 2 * 128 * NG + NG) {
    int g = idx - 2 * 128 * NG;
    bias[g] = b_ih[g] + b_hh[g];
  } else if (idx < 2 * 128 * NG + NG + XPB + 16) {
    int k = idx - (2 * 128 * NG + NG);
    flags[k] = (k < XPB) ? 0 : 1;   // 16 sentinels for the 36-wide check
  }
}

// ---------------- fused: gru (blocks 0..31) + xproj (blocks 32..2079) -------
// R10: R9 falsified the poll theory (4x amortization -> fused dispatch
// UNCHANGED+17). Remaining fused-vs-standalone delta ~90us attributed to the
// 2048 buffer_wbl2 emitted by __hip_atomic_store(RELEASE,AGENT): each xproj
// block force-writes-back its whole XCD L2 (~256x per XCD), stalling the
// co-resident gru blocks' L2 path. Fix: xp + flag stores go sc0 sc1
// (write-through to MALL, no dirty L2, no wbl2, no cache maintenance at all).
// __syncthreads' per-wave vmcnt(0) orders all xp stores (MALL-acked) before
// tid0's flag store. Consumer side unchanged.
__global__
__attribute__((amdgpu_flat_work_group_size(512, 512), amdgpu_waves_per_eu(2, 2)))
void fused_kernel(const float* __restrict__ inf,
                  const half2_t* __restrict__ wih3,
                  const float* __restrict__ bias,
                  float* __restrict__ xp,
                  const half2_t* __restrict__ whh3,
                  float* __restrict__ out,
                  int* __restrict__ flags) {
  const int tid = threadIdx.x;
  const int c   = tid & 3;        // K-quarter
  const int j1  = tid >> 2;       // j-pair index 0..127
  const int jj  = c & 1;          // owned j parity
  const int jmine = 2 * j1 + jj;

  if (blockIdx.x >= GRUB) {
    // ---------------- xproj role: one time-step (32 rows) ----------------
    const int xb = (int)blockIdx.x - GRUB;
    LOADPIN_W(wih3 + (size_t)tid * 192);
    const float bgr = bias[jmine], bgz = bias[NH + jmine], bgn = bias[2 * NH + jmine];
    const float4* fr = (const float4*)(inf + (size_t)xb * 32 * NIN + c * 64);
    float* xo = xp + (size_t)xb * 32 * NG + jmine;
    for (int rr = 0; rr < 32; ++rr) {
      float a0 = 0.f, a1 = 0.f, a2 = 0.f, a3 = 0.f, a4 = 0.f, a5 = 0.f;
      float4 g0, g1; int4 q;
#define XB(IDX, U0, U1, U2, U3, U4, U5, OFF)                                  \
      g0 = fr[2 * (IDX)]; g1 = fr[2 * (IDX) + 1];                             \
      q.x = P2I(g0.x, g0.y); q.y = P2I(g0.z, g0.w);                           \
      q.z = P2I(g1.x, g1.y); q.w = P2I(g1.z, g1.w);                           \
      DOT6(q, U0, U1, U2, U3, U4, U5, OFF);
      XB(0, W0a, W1a, W2a, W3a, W4a, W5a, 0)
      XB(1, W0a, W1a, W2a, W3a, W4a, W5a, 4)
      XB(2, W0a, W1a, W2a, W3a, W4a, W5a, 8)
      XB(3, W0a, W1a, W2a, W3a, W4a, W5a, 12)
      XB(4, W0b, W1b, W2b, W3b, W4b, W5b, 0)
      XB(5, W0b, W1b, W2b, W3b, W4b, W5b, 4)
      XB(6, W0b, W1b, W2b, W3b, W4b, W5b, 8)
      XB(7, W0b, W1b, W2b, W3b, W4b, W5b, 12)
#undef XB
      float mvr, mvz, mvn;
      QREDUCE(mvr, mvz, mvn);
      if (c < 2) {
        float vr = mvr + bgr, vz = mvz + bgz, vn = mvn + bgn;
        // write-through to MALL: no dirty XCD-L2 lines, nothing to wbl2 later
        asm volatile("global_store_dword %0, %1, off sc0 sc1\n"
                     "global_store_dword %0, %2, off offset:1024 sc0 sc1\n"
                     "global_store_dword %0, %3, off offset:2048 sc0 sc1"
                     :: "v"(xo), "v"(vr), "v"(vz), "v"(vn) : "memory");
      }
      fr += 64;   // next row (256 floats)
      xo += NG;
    }
    __syncthreads();   // per-wave vmcnt(0): all sc0sc1 xp stores MALL-acked
    if (tid == 0) {    // plain device-visible flag store; NO wbl2
      int one = 1;
      asm volatile("global_store_dword %0, %1, off sc0 sc1"
                   :: "v"(&flags[xb]), "v"(one) : "memory");
    }
    return;
  }

  // ---------------- gru role: one batch chain ----------------
  const int b = blockIdx.x;
  LOADPIN_W(whh3 + (size_t)tid * 192);

  // 2 buffers x 4 chunks x 144 B (chunk = 64 f16 + 16 B pad) = 1152 B
  __shared__ __attribute__((aligned(16))) char smh[1152];
  if (tid < 288) ((int*)smh)[tid] = 0;

  FLAGWAIT36(flags);   // rows 0..35 ready: covers preload + window-0 prefetches

  const float* xq = xp + (size_t)b * NG + jmine;
  float xr_c = xq[0], xz_c = xq[NH], xn_c = xq[2 * NH];
  xq += (size_t)BATCH * NG;
  float* op = out + (size_t)b * NH + jmine;

  const int wofs = 144 * (jmine >> 6) + 2 * (jmine & 63);

  float h = 0.f;
  __syncthreads();

#define GSTEP(RB, WB) do {                                                    \
    float xr_n = xq[0], xz_n = xq[NH], xn_n = xq[2 * NH];                     \
    const char* hb = smh + (RB) + c * 144;                                    \
    float a0 = 0.f, a1 = 0.f, a2 = 0.f, a3 = 0.f, a4 = 0.f, a5 = 0.f;        \
    int4 q0 = *(const int4*)(hb +   0), q1 = *(const int4*)(hb +  16);       \
    int4 q2 = *(const int4*)(hb +  32), q3 = *(const int4*)(hb +  48);       \
    int4 q4 = *(const int4*)(hb +  64), q5 = *(const int4*)(hb +  80);       \
    int4 q6 = *(const int4*)(hb +  96), q7 = *(const int4*)(hb + 112);       \
    DOT6x8();                                                                 \
    float mvr, mvz, mvn;                                                      \
    QREDUCE(mvr, mvz, mvn);                                                   \
    float r = sigmoid_fast(xr_c + mvr);                                       \
    float z = sigmoid_fast(xz_c + mvz);                                       \
    float n = tanh_fast(xn_c + mvn + r * mvn);  /* torch quirk */            \
    h = z * (h - n) + n;                                                      \
    if (c < 2) {                                                              \
      op[0] = h;                                                              \
      *(_Float16*)(smh + (WB) + wofs) = (_Float16)h;                          \
    }                                                                         \
    asm volatile("s_waitcnt lgkmcnt(0)\n\ts_barrier" ::: "memory");           \
    xr_c = xr_n; xz_c = xz_n; xn_c = xn_n;                                    \
    xq += (size_t)BATCH * NG;                                                 \
    op += (size_t)BATCH * NH;                                                 \
  } while (0)

  for (int t0 = 0; t0 < S_LEN; t0 += 8) {
    if (t0 && (t0 & 31) == 0) FLAGWAIT36(flags + t0);  // rows t0..t0+35
    for (int u = 0; u < 4; ++u) {
      GSTEP(0, 576);
      GSTEP(576, 0);
    }
  }
#undef GSTEP

  if (c < 2) out[(size_t)S_LEN * BATCH * NH + (size_t)b * NH + jmine] = h;
}

extern "C" void kernel_launch(void* const* d_in, const int* in_sizes, int n_in,
                              void* d_out, int out_size, void* d_ws, size_t ws_size,
                              hipStream_t stream) {
  const float* input = (const float*)d_in[0];
  const float* W_ih  = (const float*)d_in[1];
  const float* W_hh  = (const float*)d_in[2];
  const float* b_ih  = (const float*)d_in[3];
  const float* b_hh  = (const float*)d_in[4];
  float* out = (float*)d_out;

  const size_t SB = (size_t)S_LEN * BATCH;           // 65536
  const size_t xp_b = SB * NG * 4;                   // 192 MiB
  const size_t w_b  = (size_t)128 * NG * 4;          // 384 KiB each

  char* p = (char*)d_ws;
  float*    xp    = (float*)p;                p += xp_b;
  half2_t*  whh3  = (half2_t*)p;              p += w_b;
  half2_t*  wih3  = (half2_t*)p;              p += w_b;
  float*    bias  = (float*)p;                p += (size_t)NG * 4;
  uintptr_t fp_ = (((uintptr_t)p) + 127) & ~(uintptr_t)127;
  int*      flags = (int*)fp_;                // 2064 ints (2048 + 16 sentinels)

  const int prep_items = 2 * 128 * NG + NG + XPB + 16;
  prep_w_kernel<<<(prep_items + 255) / 256, 256, 0, stream>>>(W_ih, W_hh, b_ih, b_hh,
                                                              whh3, wih3, bias, flags);
  fused_kernel<<<GRUB + XPB, 512, 0, stream>>>(input, wih3, bias, xp, whh3, out, flags);
  (void)out_size; (void)n_in; (void)in_sizes; (void)ws_size;
}